// Round 1
// baseline (4639.824 us; speedup 1.0000x reference)
//
#include <hip/hip_runtime.h>
#include <math.h>

#define B 8
#define LSEQ 2500
#define EDIM 100
#define DDIM 128
#define YLAB 8921
#define KW 9

#define BYTOT (B*YLAB)   // 71368

// ws layout (float offsets)
#define OFF_H 0
#define OFF_STATS (OFF_H + B*LSEQ*DDIM)        // 2,560,000
#define OFF_M (OFF_STATS + 2*BYTOT)            // 2,702,736
#define OFF_LOGITS (OFF_M + BYTOT*DDIM)        // 11,837,840
#define OFF_WT (OFF_LOGITS + BYTOT)            // 11,909,208  (+115,200 -> ~48.1 MB)

// ---------------- conv weight transpose: (D,E,K) -> (K,E,D) for coalesced lane-d reads
__global__ __launch_bounds__(256) void k_wtrans(const float* __restrict__ w, float* __restrict__ wT) {
    int i = blockIdx.x * 256 + threadIdx.x;
    if (i >= DDIM * EDIM * KW) return;
    int k = i % KW;
    int e = (i / KW) % EDIM;
    int d = i / (KW * EDIM);
    wT[(k * EDIM + e) * DDIM + d] = w[i];
}

// ---------------- fused embedding-gather + conv1d(same) + tanh -> h [B][L][D]
#define CTL 20
__global__ __launch_bounds__(256) void k_conv(const int* __restrict__ x, const float* __restrict__ emb,
                                              const float* __restrict__ wT, const float* __restrict__ bias,
                                              float* __restrict__ h) {
    __shared__ float se[(CTL + 8) * EDIM];
    int blk = blockIdx.x;
    int b = blk / (LSEQ / CTL);
    int l0 = (blk % (LSEQ / CTL)) * CTL;
    int tid = threadIdx.x;
    for (int i = tid; i < (CTL + 8) * EDIM; i += 256) {
        int row = i / EDIM, e = i - row * EDIM;
        int l = l0 + row - 4;
        float v = 0.f;
        if (l >= 0 && l < LSEQ) {
            int tok = x[b * LSEQ + l];
            v = emb[(size_t)tok * EDIM + e];
        }
        se[i] = v;
    }
    __syncthreads();
    int d = tid & 127;
    int g = tid >> 7;  // 0..1
    float bv = bias[d];
    float acc[10];
#pragma unroll
    for (int li = 0; li < 10; li++) acc[li] = bv;
    for (int e = 0; e < EDIM; e++) {
#pragma unroll
        for (int k = 0; k < KW; k++) {
            float wv = wT[(k * EDIM + e) * DDIM + d];
#pragma unroll
            for (int li = 0; li < 10; li++) {
                acc[li] += se[(g + 2 * li + k) * EDIM + e] * wv;
            }
        }
    }
#pragma unroll
    for (int li = 0; li < 10; li++) {
        int l = l0 + g + 2 * li;
        h[((size_t)b * LSEQ + l) * DDIM + d] = tanhf(acc[li]);
    }
}

// ---------------- scores GEMM: s[b,y,l] = U[y,:]·h[b,l,:] -> written raw into alpha region
#define SYT 64
#define SLT 64
__global__ __launch_bounds__(256) void k_scores(const float* __restrict__ h, const float* __restrict__ U,
                                                float* __restrict__ sbuf) {
    __shared__ float Ut[DDIM * 68];
    __shared__ float Ht[DDIM * 68];
    int l0 = blockIdx.x * SLT;
    int y0 = blockIdx.y * SYT;
    int b = blockIdx.z;
    int tid = threadIdx.x;
    for (int i = tid; i < SYT * DDIM; i += 256) {
        int r = i >> 7, c = i & 127;
        int y = y0 + r;
        Ut[c * 68 + r] = (y < YLAB) ? U[(size_t)y * DDIM + c] : 0.f;
    }
    for (int i = tid; i < SLT * DDIM; i += 256) {
        int r = i >> 7, c = i & 127;
        int l = l0 + r;
        Ht[c * 68 + r] = (l < LSEQ) ? h[((size_t)b * LSEQ + l) * DDIM + c] : 0.f;
    }
    __syncthreads();
    int ty = (tid >> 4) * 4;
    int tl = (tid & 15) * 4;
    float acc[4][4] = {};
    for (int d = 0; d < DDIM; d++) {
        float4 uv = *(const float4*)&Ut[d * 68 + ty];
        float4 hv = *(const float4*)&Ht[d * 68 + tl];
        acc[0][0] += uv.x * hv.x; acc[0][1] += uv.x * hv.y; acc[0][2] += uv.x * hv.z; acc[0][3] += uv.x * hv.w;
        acc[1][0] += uv.y * hv.x; acc[1][1] += uv.y * hv.y; acc[1][2] += uv.y * hv.z; acc[1][3] += uv.y * hv.w;
        acc[2][0] += uv.z * hv.x; acc[2][1] += uv.z * hv.y; acc[2][2] += uv.z * hv.z; acc[2][3] += uv.z * hv.w;
        acc[3][0] += uv.w * hv.x; acc[3][1] += uv.w * hv.y; acc[3][2] += uv.w * hv.z; acc[3][3] += uv.w * hv.w;
    }
#pragma unroll
    for (int i = 0; i < 4; i++) {
        int y = y0 + ty + i;
        if (y >= YLAB) continue;
        size_t base = ((size_t)(b * YLAB + y)) * LSEQ;
#pragma unroll
        for (int j = 0; j < 4; j++) {
            int l = l0 + tl + j;
            if (l < LSEQ) sbuf[base + l] = acc[i][j];
        }
    }
}

// ---------------- softmax stats per (b,y): max and sum(exp(s-max))
__global__ __launch_bounds__(256) void k_stats(const float* __restrict__ sbuf, float2* __restrict__ stats) {
    int by = blockIdx.x;
    const float* row = sbuf + (size_t)by * LSEQ;
    int tid = threadIdx.x;
    float mx = -1e30f;
    for (int i = tid; i < LSEQ; i += 256) mx = fmaxf(mx, row[i]);
    for (int o = 32; o > 0; o >>= 1) mx = fmaxf(mx, __shfl_down(mx, o, 64));
    __shared__ float redm[4];
    if ((tid & 63) == 0) redm[tid >> 6] = mx;
    __syncthreads();
    mx = fmaxf(fmaxf(redm[0], redm[1]), fmaxf(redm[2], redm[3]));
    float sm = 0.f;
    for (int i = tid; i < LSEQ; i += 256) sm += __expf(row[i] - mx);
    for (int o = 32; o > 0; o >>= 1) sm += __shfl_down(sm, o, 64);
    __shared__ float reds[4];
    if ((tid & 63) == 0) reds[tid >> 6] = sm;
    __syncthreads();
    if (tid == 0) stats[by] = make_float2(mx, reds[0] + reds[1] + reds[2] + reds[3]);
}

// ---------------- fused: alpha = exp(s-mx)/sum (in place), m[b,y,:] = sum_l alpha*h[b,l,:]
#define PYT 32
#define PLT 64
__global__ __launch_bounds__(256) void k_pool(const float* __restrict__ h, float* __restrict__ alpha,
                                              const float2* __restrict__ stats, float* __restrict__ m) {
    __shared__ float hs[PLT][132];
    __shared__ float as[PYT][66];
    __shared__ float smx[PYT], sri[PYT];
    int y0 = blockIdx.x * PYT;
    int b = blockIdx.y;
    int tid = threadIdx.x;
    if (tid < PYT) {
        int y = y0 + tid;
        float2 s = (y < YLAB) ? stats[b * YLAB + y] : make_float2(0.f, 1.f);
        smx[tid] = s.x;
        sri[tid] = 1.f / s.y;
    }
    int ty = (tid >> 4) * 2;
    int td = (tid & 15) * 8;
    float acc[2][8] = {};
    for (int l0 = 0; l0 < LSEQ; l0 += PLT) {
        __syncthreads();
        for (int i = tid; i < PLT * DDIM; i += 256) {
            int r = i >> 7, c = i & 127;
            int l = l0 + r;
            hs[r][c] = (l < LSEQ) ? h[((size_t)b * LSEQ + l) * DDIM + c] : 0.f;
        }
        for (int i = tid; i < PYT * PLT; i += 256) {
            int r = i >> 6, c = i & 63;
            int y = y0 + r, l = l0 + c;
            float a = 0.f;
            if (y < YLAB && l < LSEQ) {
                size_t idx = ((size_t)(b * YLAB + y)) * LSEQ + l;
                a = __expf(alpha[idx] - smx[r]) * sri[r];
                alpha[idx] = a;
            }
            as[r][c] = a;
        }
        __syncthreads();
        for (int l = 0; l < PLT; l++) {
            float a0 = as[ty][l], a1 = as[ty + 1][l];
            float4 h0 = *(const float4*)&hs[l][td];
            float4 h1 = *(const float4*)&hs[l][td + 4];
            acc[0][0] += a0 * h0.x; acc[0][1] += a0 * h0.y; acc[0][2] += a0 * h0.z; acc[0][3] += a0 * h0.w;
            acc[0][4] += a0 * h1.x; acc[0][5] += a0 * h1.y; acc[0][6] += a0 * h1.z; acc[0][7] += a0 * h1.w;
            acc[1][0] += a1 * h0.x; acc[1][1] += a1 * h0.y; acc[1][2] += a1 * h0.z; acc[1][3] += a1 * h0.w;
            acc[1][4] += a1 * h1.x; acc[1][5] += a1 * h1.y; acc[1][6] += a1 * h1.z; acc[1][7] += a1 * h1.w;
        }
    }
#pragma unroll
    for (int i = 0; i < 2; i++) {
        int y = y0 + ty + i;
        if (y < YLAB) {
            float* mp = &m[((size_t)(b * YLAB + y)) * DDIM + td];
#pragma unroll
            for (int j = 0; j < 8; j++) mp[j] = acc[i][j];
        }
    }
}

// ---------------- logits + sigmoid
__global__ __launch_bounds__(256) void k_logits(const float* __restrict__ m, const float* __restrict__ fw,
                                                const float* __restrict__ fb, float* __restrict__ yhat,
                                                float* __restrict__ logits) {
    int idx = blockIdx.x * 256 + threadIdx.x;
    if (idx >= BYTOT) return;
    int y = idx % YLAB;
    const float* mv = m + (size_t)idx * DDIM;
    const float* wv = fw + (size_t)y * DDIM;
    float acc = fb[y];
#pragma unroll 8
    for (int d = 0; d < DDIM; d++) acc += wv[d] * mv[d];
    logits[idx] = acc;
    yhat[idx] = 1.f / (1.f + expf(-acc));
}

// ---------------- BCE-with-logits mean, single block
__global__ __launch_bounds__(256) void k_loss(const float* __restrict__ logits, const float* __restrict__ target,
                                              float* __restrict__ out_loss) {
    int tid = threadIdx.x;
    float sum = 0.f;
    for (int i = tid; i < BYTOT; i += 256) {
        float z = logits[i], t = target[i];
        sum += fmaxf(z, 0.f) - z * t + log1pf(expf(-fabsf(z)));
    }
    for (int o = 32; o > 0; o >>= 1) sum += __shfl_down(sum, o, 64);
    __shared__ float red[4];
    if ((tid & 63) == 0) red[tid >> 6] = sum;
    __syncthreads();
    if (tid == 0) out_loss[0] = (red[0] + red[1] + red[2] + red[3]) / (float)BYTOT;
}

extern "C" void kernel_launch(void* const* d_in, const int* in_sizes, int n_in,
                              void* d_out, int out_size, void* d_ws, size_t ws_size,
                              hipStream_t stream) {
    const int* x = (const int*)d_in[0];
    const float* target = (const float*)d_in[1];
    const float* emb = (const float*)d_in[2];
    const float* conv_w = (const float*)d_in[3];
    const float* conv_b = (const float*)d_in[4];
    const float* U = (const float*)d_in[5];
    const float* fw = (const float*)d_in[6];
    const float* fb = (const float*)d_in[7];

    float* out = (float*)d_out;
    float* yhat = out;                 // [B*Y]
    float* loss = out + BYTOT;         // [1]
    float* alpha = out + BYTOT + 1;    // [B*Y*L] — used first as raw-score scratch

    float* ws = (float*)d_ws;
    float* hbuf = ws + OFF_H;
    float2* stats = (float2*)(ws + OFF_STATS);
    float* mbuf = ws + OFF_M;
    float* logits = ws + OFF_LOGITS;
    float* wT = ws + OFF_WT;

    k_wtrans<<<(DDIM * EDIM * KW + 255) / 256, 256, 0, stream>>>(conv_w, wT);
    k_conv<<<B * (LSEQ / CTL), 256, 0, stream>>>(x, emb, wT, conv_b, hbuf);
    dim3 g3((LSEQ + SLT - 1) / SLT, (YLAB + SYT - 1) / SYT, B);
    k_scores<<<g3, 256, 0, stream>>>(hbuf, U, alpha);
    k_stats<<<BYTOT, 256, 0, stream>>>(alpha, stats);
    dim3 g6((YLAB + PYT - 1) / PYT, B);
    k_pool<<<g6, 256, 0, stream>>>(hbuf, alpha, stats, mbuf);
    k_logits<<<(BYTOT + 255) / 256, 256, 0, stream>>>(mbuf, fw, fb, yhat, logits);
    k_loss<<<1, 256, 0, stream>>>(logits, target, loss);
}

// Round 2
// 1495.134 us; speedup vs baseline: 3.1033x; 3.1033x over previous
//
#include <hip/hip_runtime.h>
#include <math.h>

#define B 8
#define LSEQ 2500
#define EDIM 100
#define DDIM 128
#define YLAB 8921
#define KW 9
#define BYTOT (B*YLAB)   // 71368
#define LP 2528          // padded L for hT (79*32)
#define NLB 40           // l-blocks of 64 in scores

typedef __attribute__((ext_vector_type(8))) short bf16x8;
typedef __attribute__((ext_vector_type(4))) float f32x4;

__device__ __forceinline__ ushort f2bf(float f){
    union { float f; unsigned u; } v; v.f = f;
    unsigned r = v.u + 0x7FFFu + ((v.u >> 16) & 1u);
    return (ushort)(r >> 16);
}

// ---- ws float offsets ----
#define OFF_HB 0                 // h bf16 [B][L][128]   : 2,560,000 ush = 1,280,000 fl
#define OFF_HT 1280000           // hT bf16 [B][128][LP] : 2,588,672 ush = 1,294,336 fl
#define OFF_UB 2574336           // U bf16 [Y][128]      : 1,141,888 ush = 570,944 fl
#define OFF_PS 3145280           // psum [B][Y][NLB]     : 2,854,720 fl
#define OFF_RI 6000000           // rinv [B*Y]
#define OFF_LG 6071368           // logits [B*Y]
#define OFF_WT 6142736           // conv wT 115,200 fl   -> total ~25 MB

// ---------------- prep: conv-weight transpose + U->bf16 + hT pad zeroing
#define NP1 (DDIM*EDIM*KW)          // 115200
#define NP2 (YLAB*DDIM)             // 1141888
#define NP3 (B*DDIM*(LP-LSEQ))      // 28672
__global__ __launch_bounds__(256) void k_prep(const float* __restrict__ w, const float* __restrict__ U,
                                              float* __restrict__ wT, ushort* __restrict__ Ub,
                                              ushort* __restrict__ hT){
    int i = blockIdx.x * 256 + threadIdx.x;
    if (i < NP1) {
        int k = i % KW, e = (i / KW) % EDIM, d = i / (KW * EDIM);
        wT[(k * EDIM + e) * DDIM + d] = w[i];
    }
    int i2 = i - NP1;
    if (i2 >= 0 && i2 < NP2) Ub[i2] = f2bf(U[i2]);
    int i3 = i - NP1 - NP2;
    if (i3 >= 0 && i3 < NP3) {
        int c = i3 % (LP - LSEQ), bd = i3 / (LP - LSEQ);
        hT[(size_t)bd * LP + LSEQ + c] = 0;
    }
}

// ---------------- fused embed + conv1d + tanh -> h bf16 [B][L][128] and hT bf16 [B][128][LP]
#define CTL 20
__global__ __launch_bounds__(256) void k_conv(const int* __restrict__ x, const float* __restrict__ emb,
                                              const float* __restrict__ wT, const float* __restrict__ bias,
                                              ushort* __restrict__ hb, ushort* __restrict__ hT) {
    __shared__ float se[(CTL + 8) * EDIM];
    __shared__ ushort hstage[DDIM][CTL + 2];
    int blk = blockIdx.x;
    int b = blk / (LSEQ / CTL);
    int l0 = (blk % (LSEQ / CTL)) * CTL;
    int tid = threadIdx.x;
    for (int i = tid; i < (CTL + 8) * EDIM; i += 256) {
        int row = i / EDIM, e = i - row * EDIM;
        int l = l0 + row - 4;
        float v = 0.f;
        if (l >= 0 && l < LSEQ) {
            int tok = x[b * LSEQ + l];
            v = emb[(size_t)tok * EDIM + e];
        }
        se[i] = v;
    }
    __syncthreads();
    int d = tid & 127;
    int g = tid >> 7;  // 0..1
    float bv = bias[d];
    float acc[10];
#pragma unroll
    for (int li = 0; li < 10; li++) acc[li] = bv;
    for (int e = 0; e < EDIM; e++) {
#pragma unroll
        for (int k = 0; k < KW; k++) {
            float wv = wT[(k * EDIM + e) * DDIM + d];
#pragma unroll
            for (int li = 0; li < 10; li++) {
                acc[li] += se[(g + 2 * li + k) * EDIM + e] * wv;
            }
        }
    }
#pragma unroll
    for (int li = 0; li < 10; li++) {
        int l = l0 + g + 2 * li;
        ushort u = f2bf(tanhf(acc[li]));
        hb[((size_t)b * LSEQ + l) * DDIM + d] = u;
        hstage[d][g + 2 * li] = u;
    }
    __syncthreads();
    int d2 = tid >> 1, half = tid & 1;
    size_t base = ((size_t)b * DDIM + d2) * LP + l0 + half * 10;
#pragma unroll
    for (int q = 0; q < 10; q++) hT[base + q] = hstage[d2][half * 10 + q];
}

// ---------------- scores via MFMA: e = exp(U·h^T) -> alpha region + per-block partial sums
__global__ __launch_bounds__(256) void k_scores(const ushort* __restrict__ hb, const ushort* __restrict__ Ub,
                                                float* __restrict__ alpha, float* __restrict__ psum) {
    int lblk = blockIdx.x, yblk = blockIdx.y, b = blockIdx.z;
    int l0 = lblk * 64, y0 = yblk * 64;
    int tid = threadIdx.x, w = tid >> 6, lane = tid & 63, g = lane >> 4, ln = lane & 15;
    int wy = w >> 1, wl = w & 1;
    int y0w = y0 + wy * 32, l0w = l0 + wl * 32;
    int yA0 = y0w + ln, yA1 = yA0 + 16;
    int lB0 = l0w + ln, lB1 = lB0 + 16;
    const ushort* Ap0 = Ub + (size_t)yA0 * DDIM + g * 8;
    const ushort* Ap1 = Ub + (size_t)yA1 * DDIM + g * 8;
    const ushort* Bp0 = hb + ((size_t)b * LSEQ + lB0) * DDIM + g * 8;
    const ushort* Bp1 = hb + ((size_t)b * LSEQ + lB1) * DDIM + g * 8;
    bool va0 = yA0 < YLAB, va1 = yA1 < YLAB, vb0 = lB0 < LSEQ, vb1 = lB1 < LSEQ;
    f32x4 zero4 = {0.f, 0.f, 0.f, 0.f};
    f32x4 acc[2][2];
    acc[0][0] = zero4; acc[0][1] = zero4; acc[1][0] = zero4; acc[1][1] = zero4;
    bf16x8 zf = {0, 0, 0, 0, 0, 0, 0, 0};
#pragma unroll
    for (int kk = 0; kk < 4; kk++) {
        bf16x8 a0 = va0 ? *(const bf16x8*)(Ap0 + kk * 32) : zf;
        bf16x8 a1 = va1 ? *(const bf16x8*)(Ap1 + kk * 32) : zf;
        bf16x8 b0 = vb0 ? *(const bf16x8*)(Bp0 + kk * 32) : zf;
        bf16x8 b1 = vb1 ? *(const bf16x8*)(Bp1 + kk * 32) : zf;
        acc[0][0] = __builtin_amdgcn_mfma_f32_16x16x32_bf16(a0, b0, acc[0][0], 0, 0, 0);
        acc[0][1] = __builtin_amdgcn_mfma_f32_16x16x32_bf16(a0, b1, acc[0][1], 0, 0, 0);
        acc[1][0] = __builtin_amdgcn_mfma_f32_16x16x32_bf16(a1, b0, acc[1][0], 0, 0, 0);
        acc[1][1] = __builtin_amdgcn_mfma_f32_16x16x32_bf16(a1, b1, acc[1][1], 0, 0, 0);
    }
    float ts[2][4] = {};
#pragma unroll
    for (int fy = 0; fy < 2; fy++)
#pragma unroll
        for (int fl = 0; fl < 2; fl++)
#pragma unroll
            for (int j = 0; j < 4; j++) {
                int y = y0w + fy * 16 + g * 4 + j;
                int l = l0w + fl * 16 + ln;
                bool v = (y < YLAB) && (l < LSEQ);
                float e = v ? __expf(acc[fy][fl][j]) : 0.f;
                if (v) alpha[(size_t)(b * YLAB + y) * LSEQ + l] = e;
                ts[fy][j] += e;
            }
#pragma unroll
    for (int fy = 0; fy < 2; fy++)
#pragma unroll
        for (int j = 0; j < 4; j++) {
            float t = ts[fy][j];
            t += __shfl_xor(t, 1, 64); t += __shfl_xor(t, 2, 64);
            t += __shfl_xor(t, 4, 64); t += __shfl_xor(t, 8, 64);
            ts[fy][j] = t;
        }
    __shared__ float psl[2][64];
    if (ln == 0) {
#pragma unroll
        for (int fy = 0; fy < 2; fy++)
#pragma unroll
            for (int j = 0; j < 4; j++)
                psl[wl][wy * 32 + fy * 16 + g * 4 + j] = ts[fy][j];
    }
    __syncthreads();
    if (tid < 64) {
        int y = y0 + tid;
        if (y < YLAB) psum[(size_t)(b * YLAB + y) * NLB + lblk] = psl[0][tid] + psl[1][tid];
    }
}

// ---------------- rinv = 1/sum over l-blocks
__global__ __launch_bounds__(256) void k_rinv(const float* __restrict__ psum, float* __restrict__ rinv) {
    int i = blockIdx.x * 256 + threadIdx.x;
    if (i >= BYTOT) return;
    const float* p = psum + (size_t)i * NLB;
    float s = 0.f;
#pragma unroll
    for (int j = 0; j < NLB; j++) s += p[j];
    rinv[i] = 1.f / s;
}

// ---------------- pool via MFMA: alpha normalize (in place) + m = alpha·h + fused logits/sigmoid
__global__ __launch_bounds__(256) void k_pool(float* __restrict__ alpha, const ushort* __restrict__ hT,
                                              const float* __restrict__ rinv, const float* __restrict__ fw,
                                              const float* __restrict__ fb, float* __restrict__ yhat,
                                              float* __restrict__ logits) {
    int y0 = blockIdx.x * 64, b = blockIdx.y;
    int tid = threadIdx.x, w = tid >> 6, lane = tid & 63, g = lane >> 4, ln = lane & 15;
    int ya = y0 + w * 16 + ln;
    bool vy = ya < YLAB;
    int yc = vy ? ya : (YLAB - 1);
    float rv = vy ? rinv[b * YLAB + yc] : 0.f;
    float* arow = alpha + (size_t)(b * YLAB + yc) * LSEQ + g * 8;
    const ushort* bb = hT + ((size_t)b * DDIM + ln) * LP + g * 8;
    f32x4 zero4 = {0.f, 0.f, 0.f, 0.f};
    f32x4 acc[8];
#pragma unroll
    for (int fd = 0; fd < 8; fd++) acc[fd] = zero4;
    for (int l0 = 0; l0 < LP; l0 += 32) {
        float an[8];
        if (l0 + 32 <= LSEQ) {
#pragma unroll
            for (int j = 0; j < 8; j++) an[j] = arow[l0 + j] * rv;
            if (vy) {
#pragma unroll
                for (int j = 0; j < 8; j++) arow[l0 + j] = an[j];
            }
        } else {
#pragma unroll
            for (int j = 0; j < 8; j++) {
                int l = l0 + g * 8 + j;
                float e = (l < LSEQ) ? arow[l0 + j] : 0.f;
                an[j] = e * rv;
                if (vy && l < LSEQ) arow[l0 + j] = an[j];
            }
        }
        bf16x8 af;
#pragma unroll
        for (int j = 0; j < 8; j++) af[j] = (short)f2bf(an[j]);
#pragma unroll
        for (int fd = 0; fd < 8; fd++) {
            bf16x8 bfv = *(const bf16x8*)(bb + (size_t)fd * 16 * LP + l0);
            acc[fd] = __builtin_amdgcn_mfma_f32_16x16x32_bf16(af, bfv, acc[fd], 0, 0, 0);
        }
    }
    // fused logits: lp[j] = sum_d acc * fw
    float lp[4] = {0.f, 0.f, 0.f, 0.f};
#pragma unroll
    for (int j = 0; j < 4; j++) {
        int yr = y0 + w * 16 + g * 4 + j;
        bool vr = yr < YLAB;
#pragma unroll
        for (int fd = 0; fd < 8; fd++) {
            float fwv = vr ? fw[(size_t)yr * DDIM + fd * 16 + ln] : 0.f;
            lp[j] += acc[fd][j] * fwv;
        }
    }
#pragma unroll
    for (int j = 0; j < 4; j++) {
        float t = lp[j];
        t += __shfl_xor(t, 1, 64); t += __shfl_xor(t, 2, 64);
        t += __shfl_xor(t, 4, 64); t += __shfl_xor(t, 8, 64);
        lp[j] = t;
    }
    if (ln == 0) {
#pragma unroll
        for (int j = 0; j < 4; j++) {
            int yr = y0 + w * 16 + g * 4 + j;
            if (yr < YLAB) {
                float lg = lp[j] + fb[yr];
                int idx = b * YLAB + yr;
                logits[idx] = lg;
                yhat[idx] = 1.f / (1.f + expf(-lg));
            }
        }
    }
}

// ---------------- BCE-with-logits mean
__global__ __launch_bounds__(256) void k_loss(const float* __restrict__ logits, const float* __restrict__ target,
                                              float* __restrict__ out_loss) {
    int tid = threadIdx.x;
    float sum = 0.f;
    for (int i = tid; i < BYTOT; i += 256) {
        float z = logits[i], t = target[i];
        sum += fmaxf(z, 0.f) - z * t + log1pf(expf(-fabsf(z)));
    }
    for (int o = 32; o > 0; o >>= 1) sum += __shfl_down(sum, o, 64);
    __shared__ float red[4];
    if ((tid & 63) == 0) red[tid >> 6] = sum;
    __syncthreads();
    if (tid == 0) out_loss[0] = (red[0] + red[1] + red[2] + red[3]) / (float)BYTOT;
}

extern "C" void kernel_launch(void* const* d_in, const int* in_sizes, int n_in,
                              void* d_out, int out_size, void* d_ws, size_t ws_size,
                              hipStream_t stream) {
    const int* x = (const int*)d_in[0];
    const float* target = (const float*)d_in[1];
    const float* emb = (const float*)d_in[2];
    const float* conv_w = (const float*)d_in[3];
    const float* conv_b = (const float*)d_in[4];
    const float* U = (const float*)d_in[5];
    const float* fw = (const float*)d_in[6];
    const float* fb = (const float*)d_in[7];

    float* out = (float*)d_out;
    float* yhat = out;                 // [B*Y]
    float* loss = out + BYTOT;         // [1]
    float* alpha = out + BYTOT + 1;    // [B*Y*L] — holds raw exp-scores, then normalized alpha

    float* ws = (float*)d_ws;
    ushort* hb = (ushort*)(ws + OFF_HB);
    ushort* hT = (ushort*)(ws + OFF_HT);
    ushort* Ub = (ushort*)(ws + OFF_UB);
    float* psum = ws + OFF_PS;
    float* rinv = ws + OFF_RI;
    float* logits = ws + OFF_LG;
    float* wT = ws + OFF_WT;

    k_prep<<<(NP1 + NP2 + NP3 + 255) / 256, 256, 0, stream>>>(conv_w, U, wT, Ub, hT);
    k_conv<<<B * (LSEQ / CTL), 256, 0, stream>>>(x, emb, wT, conv_b, hb, hT);
    dim3 gs(NLB, (YLAB + 63) / 64, B);
    k_scores<<<gs, 256, 0, stream>>>(hb, Ub, alpha, psum);
    k_rinv<<<(BYTOT + 255) / 256, 256, 0, stream>>>(psum, rinv);
    dim3 gp((YLAB + 63) / 64, B);
    k_pool<<<gp, 256, 0, stream>>>(alpha, hT, rinv, fw, fb, yhat, logits);
    k_loss<<<1, 256, 0, stream>>>(logits, target, loss);
}

// Round 4
// 990.515 us; speedup vs baseline: 4.6843x; 1.5095x over previous
//
#include <hip/hip_runtime.h>
#include <math.h>

#define B 8
#define LSEQ 2500
#define EDIM 100
#define DDIM 128
#define YLAB 8921
#define KW 9
#define BYTOT (B*YLAB)   // 71368
#define LP 2528          // padded L (79*32)
#define NLB 40           // l-blocks of 64 in k_sums

typedef __attribute__((ext_vector_type(8))) short bf16x8;
typedef __attribute__((ext_vector_type(8))) unsigned short u16x8;
typedef __attribute__((ext_vector_type(4))) float f32x4;

__device__ __forceinline__ ushort f2bf(float f){
    union { float f; unsigned u; } v; v.f = f;
    unsigned r = v.u + 0x7FFFu + ((v.u >> 16) & 1u);
    return (ushort)(r >> 16);
}

// ---- ws float offsets ----
#define OFF_HB 0                 // hb bf16 [B][LP][128] : 1,294,336 fl
#define OFF_HT 1294336           // hT bf16 [B][128][LP] : 1,294,336 fl
#define OFF_UB 2588672           // U bf16 [Y][128]      : 570,944 fl
#define OFF_PS 3159616           // psum [B][Y][NLB]     : 2,854,720 fl
#define OFF_RI 6014336           // rinv [B*Y]
#define OFF_LG 6085704           // logits [B*Y]
#define OFF_WT 6157072           // conv wT 115,200 fl -> end ~25.1 MB

// ---------------- prep: conv-w transpose + U->bf16 + hT pad zero + hb pad zero
#define NP1 (DDIM*EDIM*KW)          // 115200
#define NP2 (YLAB*DDIM)             // 1141888
#define NP3 (B*DDIM*(LP-LSEQ))      // 28672
#define NP4 (B*(LP-LSEQ)*DDIM)      // 28672
__global__ __launch_bounds__(256) void k_prep(const float* __restrict__ w, const float* __restrict__ U,
                                              float* __restrict__ wT, ushort* __restrict__ Ub,
                                              ushort* __restrict__ hT, ushort* __restrict__ hb){
    int i = blockIdx.x * 256 + threadIdx.x;
    if (i < NP1) {
        int k = i % KW, e = (i / KW) % EDIM, d = i / (KW * EDIM);
        wT[(k * EDIM + e) * DDIM + d] = w[i];
    }
    int i2 = i - NP1;
    if (i2 >= 0 && i2 < NP2) Ub[i2] = f2bf(U[i2]);
    int i3 = i - NP1 - NP2;
    if (i3 >= 0 && i3 < NP3) {
        int c = i3 % (LP - LSEQ), bd = i3 / (LP - LSEQ);
        hT[(size_t)bd * LP + LSEQ + c] = 0;
    }
    int i4 = i - NP1 - NP2 - NP3;
    if (i4 >= 0 && i4 < NP4) {
        int b = i4 / ((LP - LSEQ) * DDIM);
        int r = i4 % ((LP - LSEQ) * DDIM);
        int l = LSEQ + r / DDIM, d = r % DDIM;
        hb[((size_t)b * LP + l) * DDIM + d] = 0;
    }
}

// ---------------- fused embed + conv1d + tanh -> hb bf16 [B][LP][128] and hT bf16 [B][128][LP]
#define CTL 20
__global__ __launch_bounds__(256) void k_conv(const int* __restrict__ x, const float* __restrict__ emb,
                                              const float* __restrict__ wT, const float* __restrict__ bias,
                                              ushort* __restrict__ hb, ushort* __restrict__ hT) {
    __shared__ float se[(CTL + 8) * EDIM];
    __shared__ ushort hstage[DDIM][CTL + 2];
    int blk = blockIdx.x;
    int b = blk / (LSEQ / CTL);
    int l0 = (blk % (LSEQ / CTL)) * CTL;
    int tid = threadIdx.x;
    for (int i = tid; i < (CTL + 8) * EDIM; i += 256) {
        int row = i / EDIM, e = i - row * EDIM;
        int l = l0 + row - 4;
        float v = 0.f;
        if (l >= 0 && l < LSEQ) {
            int tok = x[b * LSEQ + l];
            v = emb[(size_t)tok * EDIM + e];
        }
        se[i] = v;
    }
    __syncthreads();
    int d = tid & 127;
    int g = tid >> 7;  // 0..1
    float bv = bias[d];
    float acc[10];
#pragma unroll
    for (int li = 0; li < 10; li++) acc[li] = bv;
    for (int e = 0; e < EDIM; e++) {
#pragma unroll
        for (int k = 0; k < KW; k++) {
            float wv = wT[(k * EDIM + e) * DDIM + d];
#pragma unroll
            for (int li = 0; li < 10; li++) {
                acc[li] += se[(g + 2 * li + k) * EDIM + e] * wv;
            }
        }
    }
#pragma unroll
    for (int li = 0; li < 10; li++) {
        int l = l0 + g + 2 * li;
        ushort u = f2bf(tanhf(acc[li]));
        hb[((size_t)b * LP + l) * DDIM + d] = u;
        hstage[d][g + 2 * li] = u;
    }
    __syncthreads();
    int d2 = tid >> 1, half = tid & 1;
    size_t base = ((size_t)b * DDIM + d2) * LP + l0 + half * 10;
#pragma unroll
    for (int q = 0; q < 10; q++) hT[base + q] = hstage[d2][half * 10 + q];
}

// ---------------- softmax sums via MFMA: psum[b,y,lblk] = sum_l exp(U·h)
__global__ __launch_bounds__(256) void k_sums(const ushort* __restrict__ hb, const ushort* __restrict__ Ub,
                                              float* __restrict__ psum) {
    int lblk = blockIdx.x, yblk = blockIdx.y, b = blockIdx.z;
    int l0 = lblk * 64, y0 = yblk * 64;
    int tid = threadIdx.x, w = tid >> 6, lane = tid & 63, g = lane >> 4, ln = lane & 15;
    int wy = w >> 1, wl = w & 1;
    int y0w = y0 + wy * 32, l0w = l0 + wl * 32;
    int yA0 = y0w + ln, yA1 = yA0 + 16;
    int lB0 = l0w + ln, lB1 = lB0 + 16;
    const ushort* Ap0 = Ub + (size_t)yA0 * DDIM + g * 8;
    const ushort* Ap1 = Ub + (size_t)yA1 * DDIM + g * 8;
    const ushort* Bp0 = hb + ((size_t)b * LP + lB0) * DDIM + g * 8;
    const ushort* Bp1 = hb + ((size_t)b * LP + lB1) * DDIM + g * 8;
    bool va0 = yA0 < YLAB, va1 = yA1 < YLAB, vb0 = lB0 < LSEQ, vb1 = lB1 < LSEQ;
    f32x4 zero4 = {0.f, 0.f, 0.f, 0.f};
    f32x4 acc[2][2];
    acc[0][0] = zero4; acc[0][1] = zero4; acc[1][0] = zero4; acc[1][1] = zero4;
    bf16x8 zf = {0, 0, 0, 0, 0, 0, 0, 0};
#pragma unroll
    for (int kk = 0; kk < 4; kk++) {
        bf16x8 a0 = va0 ? *(const bf16x8*)(Ap0 + kk * 32) : zf;
        bf16x8 a1 = va1 ? *(const bf16x8*)(Ap1 + kk * 32) : zf;
        bf16x8 b0 = vb0 ? *(const bf16x8*)(Bp0 + kk * 32) : zf;
        bf16x8 b1 = vb1 ? *(const bf16x8*)(Bp1 + kk * 32) : zf;
        acc[0][0] = __builtin_amdgcn_mfma_f32_16x16x32_bf16(a0, b0, acc[0][0], 0, 0, 0);
        acc[0][1] = __builtin_amdgcn_mfma_f32_16x16x32_bf16(a0, b1, acc[0][1], 0, 0, 0);
        acc[1][0] = __builtin_amdgcn_mfma_f32_16x16x32_bf16(a1, b0, acc[1][0], 0, 0, 0);
        acc[1][1] = __builtin_amdgcn_mfma_f32_16x16x32_bf16(a1, b1, acc[1][1], 0, 0, 0);
    }
    float ts[2][4] = {};
#pragma unroll
    for (int fy = 0; fy < 2; fy++)
#pragma unroll
        for (int fl = 0; fl < 2; fl++)
#pragma unroll
            for (int j = 0; j < 4; j++) {
                int y = y0w + fy * 16 + g * 4 + j;
                int l = l0w + fl * 16 + ln;
                bool v = (y < YLAB) && (l < LSEQ);
                float e = v ? __expf(acc[fy][fl][j]) : 0.f;
                ts[fy][j] += e;
            }
#pragma unroll
    for (int fy = 0; fy < 2; fy++)
#pragma unroll
        for (int j = 0; j < 4; j++) {
            float t = ts[fy][j];
            t += __shfl_xor(t, 1, 64); t += __shfl_xor(t, 2, 64);
            t += __shfl_xor(t, 4, 64); t += __shfl_xor(t, 8, 64);
            ts[fy][j] = t;
        }
    __shared__ float psl[2][64];
    if (ln == 0) {
#pragma unroll
        for (int fy = 0; fy < 2; fy++)
#pragma unroll
            for (int j = 0; j < 4; j++)
                psl[wl][wy * 32 + fy * 16 + g * 4 + j] = ts[fy][j];
    }
    __syncthreads();
    if (tid < 64) {
        int y = y0 + tid;
        if (y < YLAB) psum[(size_t)(b * YLAB + y) * NLB + lblk] = psl[0][tid] + psl[1][tid];
    }
}

// ---------------- rinv = 1/sum over l-blocks
__global__ __launch_bounds__(256) void k_rinv(const float* __restrict__ psum, float* __restrict__ rinv) {
    int i = blockIdx.x * 256 + threadIdx.x;
    if (i >= BYTOT) return;
    const float* p = psum + (size_t)i * NLB;
    float s = 0.f;
#pragma unroll
    for (int j = 0; j < NLB; j++) s += p[j];
    rinv[i] = 1.f / s;
}

// ---------------- fused: recompute scores, alpha = exp*rinv (single write), pool MFMA, logits
__global__ __launch_bounds__(256) void k_pool(const ushort* __restrict__ hb, const ushort* __restrict__ hT,
                                              const ushort* __restrict__ Ub, const float* __restrict__ rinv,
                                              const float* __restrict__ fw, const float* __restrict__ fb,
                                              float* __restrict__ alpha, float* __restrict__ yhat,
                                              float* __restrict__ logits) {
    __shared__ ushort hbs[32 * 128];      // [l 32][xor-swizzled 16 segs of 8], 8 KB
    __shared__ ushort hts[128 * 40];      // [d 128][l 32 pad 40], 10 KB (2-way conflict only)
    __shared__ ushort et[4][16 * 40];     // per-wave E transpose tile [y 16][l 32 pad 40]
    int b = blockIdx.y;
    int y0 = blockIdx.x * 64;
    int tid = threadIdx.x, w = tid >> 6, lane = tid & 63, g = lane >> 4, ln = lane & 15;
    int y0w = y0 + w * 16;
    int ya = y0w + ln;
    bool vya = ya < YLAB;
    bf16x8 zf = {0, 0, 0, 0, 0, 0, 0, 0};
    const ushort* Ap = Ub + (size_t)ya * DDIM + g * 8;
    bf16x8 au[4];
#pragma unroll
    for (int kk = 0; kk < 4; kk++) au[kk] = vya ? *(const bf16x8*)(Ap + kk * 32) : zf;
    float rv[4];
#pragma unroll
    for (int j = 0; j < 4; j++) {
        int y = y0w + g * 4 + j;
        rv[j] = (y < YLAB) ? rinv[b * YLAB + y] : 0.f;
    }
    f32x4 zero4 = {0.f, 0.f, 0.f, 0.f};
    f32x4 accm[8];
#pragma unroll
    for (int fd = 0; fd < 8; fd++) accm[fd] = zero4;

    // staging slots:
    //   hb: 512 slots, slot s -> l = s>>4 (0..31), seg = s&15
    //   hT: 512 slots, slot s -> d = s>>2 (0..127), quarter q = s&3 (l-offset q*8)
    int s0 = tid, s1 = tid + 256;
    const ushort* hbB = hb + (size_t)b * LP * DDIM;
    const ushort* htB = hT + (size_t)b * DDIM * LP;
    int l_a = s0 >> 4, sg_a = s0 & 15, l_b = s1 >> 4, sg_b = s1 & 15;
    int d_a = s0 >> 2, q_a = s0 & 3, d_b = s1 >> 2, q_b = s1 & 3;
    int wsg_a = sg_a ^ (l_a & 7), wsg_b = sg_b ^ (l_b & 7);
    u16x8 rhb0, rhb1, rht0, rht1;
    {   // prologue loads for tile 0
        rhb0 = *(const u16x8*)(hbB + (size_t)l_a * DDIM + sg_a * 8);
        rhb1 = *(const u16x8*)(hbB + (size_t)l_b * DDIM + sg_b * 8);
        rht0 = *(const u16x8*)(htB + (size_t)d_a * LP + q_a * 8);
        rht1 = *(const u16x8*)(htB + (size_t)d_b * LP + q_b * 8);
    }

    for (int l0 = 0; l0 < LP; l0 += 32) {
        // commit staged regs to LDS
        *(u16x8*)&hbs[l_a * DDIM + wsg_a * 8] = rhb0;
        *(u16x8*)&hbs[l_b * DDIM + wsg_b * 8] = rhb1;
        *(u16x8*)&hts[d_a * 40 + q_a * 8] = rht0;
        *(u16x8*)&hts[d_b * 40 + q_b * 8] = rht1;
        __syncthreads();
        // issue next-tile loads (fly during compute)
        if (l0 + 32 < LP) {
            int ln0 = l0 + 32;
            rhb0 = *(const u16x8*)(hbB + (size_t)(ln0 + l_a) * DDIM + sg_a * 8);
            rhb1 = *(const u16x8*)(hbB + (size_t)(ln0 + l_b) * DDIM + sg_b * 8);
            rht0 = *(const u16x8*)(htB + (size_t)d_a * LP + ln0 + q_a * 8);
            rht1 = *(const u16x8*)(htB + (size_t)d_b * LP + ln0 + q_b * 8);
        }
        // scores: C[y-rel = g*4+j][l-rel = fl*16+ln]
        f32x4 sc[2];
        sc[0] = zero4; sc[1] = zero4;
#pragma unroll
        for (int kk = 0; kk < 4; kk++) {
#pragma unroll
            for (int fl = 0; fl < 2; fl++) {
                int lrow = fl * 16 + ln;
                int slotr = (kk * 4 + g) ^ (lrow & 7);
                bf16x8 bv = *(const bf16x8*)&hbs[lrow * DDIM + slotr * 8];
                sc[fl] = __builtin_amdgcn_mfma_f32_16x16x32_bf16(au[kk], bv, sc[fl], 0, 0, 0);
            }
        }
        // exp * rinv -> alpha store + E transpose tile
#pragma unroll
        for (int fl = 0; fl < 2; fl++) {
            int l = l0 + fl * 16 + ln;
#pragma unroll
            for (int j = 0; j < 4; j++) {
                float an = __expf(sc[fl][j]) * rv[j];
                int y = y0w + g * 4 + j;
                if (y < YLAB && l < LSEQ) alpha[((size_t)(b * YLAB + y)) * LSEQ + l] = an;
                et[w][(g * 4 + j) * 40 + fl * 16 + ln] = f2bf(an);
            }
        }
        // pool: A = E tile (lane ln -> y-rel ln, k = l), B = hT tile rows d
        bf16x8 af = *(const bf16x8*)&et[w][ln * 40 + g * 8];
#pragma unroll
        for (int fd = 0; fd < 8; fd++) {
            bf16x8 bt = *(const bf16x8*)&hts[(fd * 16 + ln) * 40 + g * 8];
            accm[fd] = __builtin_amdgcn_mfma_f32_16x16x32_bf16(af, bt, accm[fd], 0, 0, 0);
        }
        __syncthreads();
    }
    // fused logits epilogue: accm[fd][j] = m[y0w+g*4+j][fd*16+ln] (already rinv-scaled)
    float lp[4] = {0.f, 0.f, 0.f, 0.f};
#pragma unroll
    for (int j = 0; j < 4; j++) {
        int yr = y0w + g * 4 + j;
        bool vr = yr < YLAB;
#pragma unroll
        for (int fd = 0; fd < 8; fd++) {
            float fwv = vr ? fw[(size_t)yr * DDIM + fd * 16 + ln] : 0.f;
            lp[j] += accm[fd][j] * fwv;
        }
    }
#pragma unroll
    for (int j = 0; j < 4; j++) {
        float t = lp[j];
        t += __shfl_xor(t, 1, 64); t += __shfl_xor(t, 2, 64);
        t += __shfl_xor(t, 4, 64); t += __shfl_xor(t, 8, 64);
        lp[j] = t;
    }
    if (ln == 0) {
#pragma unroll
        for (int j = 0; j < 4; j++) {
            int yr = y0w + g * 4 + j;
            if (yr < YLAB) {
                float lg = lp[j] + fb[yr];
                int idx = b * YLAB + yr;
                logits[idx] = lg;
                yhat[idx] = 1.f / (1.f + expf(-lg));
            }
        }
    }
}

// ---------------- BCE-with-logits mean
__global__ __launch_bounds__(256) void k_loss(const float* __restrict__ logits, const float* __restrict__ target,
                                              float* __restrict__ out_loss) {
    int tid = threadIdx.x;
    float sum = 0.f;
    for (int i = tid; i < BYTOT; i += 256) {
        float z = logits[i], t = target[i];
        sum += fmaxf(z, 0.f) - z * t + log1pf(expf(-fabsf(z)));
    }
    for (int o = 32; o > 0; o >>= 1) sum += __shfl_down(sum, o, 64);
    __shared__ float red[4];
    if ((tid & 63) == 0) red[tid >> 6] = sum;
    __syncthreads();
    if (tid == 0) out_loss[0] = (red[0] + red[1] + red[2] + red[3]) / (float)BYTOT;
}

extern "C" void kernel_launch(void* const* d_in, const int* in_sizes, int n_in,
                              void* d_out, int out_size, void* d_ws, size_t ws_size,
                              hipStream_t stream) {
    const int* x = (const int*)d_in[0];
    const float* target = (const float*)d_in[1];
    const float* emb = (const float*)d_in[2];
    const float* conv_w = (const float*)d_in[3];
    const float* conv_b = (const float*)d_in[4];
    const float* U = (const float*)d_in[5];
    const float* fw = (const float*)d_in[6];
    const float* fb = (const float*)d_in[7];

    float* out = (float*)d_out;
    float* yhat = out;
    float* loss = out + BYTOT;
    float* alpha = out + BYTOT + 1;

    float* ws = (float*)d_ws;
    ushort* hb = (ushort*)(ws + OFF_HB);
    ushort* hT = (ushort*)(ws + OFF_HT);
    ushort* Ub = (ushort*)(ws + OFF_UB);
    float* psum = ws + OFF_PS;
    float* rinv = ws + OFF_RI;
    float* logits = ws + OFF_LG;
    float* wT = ws + OFF_WT;

    k_prep<<<(NP1 + NP2 + NP3 + NP4 + 255) / 256, 256, 0, stream>>>(conv_w, U, wT, Ub, hT, hb);
    k_conv<<<B * (LSEQ / CTL), 256, 0, stream>>>(x, emb, wT, conv_b, hb, hT);
    dim3 gs(NLB, (YLAB + 63) / 64, B);
    k_sums<<<gs, 256, 0, stream>>>(hb, Ub, psum);
    k_rinv<<<(BYTOT + 255) / 256, 256, 0, stream>>>(psum, rinv);
    dim3 gp((YLAB + 63) / 64, B);
    k_pool<<<gp, 256, 0, stream>>>(hb, hT, Ub, rinv, fw, fb, alpha, yhat, logits);
    k_loss<<<1, 256, 0, stream>>>(logits, target, loss);
}